// Round 1
// baseline (2998.724 us; speedup 1.0000x reference)
//
#include <hip/hip_runtime.h>
#include <hip/hip_bf16.h>
#include <math.h>

#define B_  64
#define S_  16
#define T_  48
#define E_  300
#define H_  150
#define G_  300   // 2H
#define NC_ 300
#define NW_ (B_*S_)     // 1024 word-level batch
#define RW_ (T_*NW_)    // 49152 word rows
#define RS_ (S_*B_)     // 1024 sentence rows

__device__ __forceinline__ float sigm(float x){ return 1.0f/(1.0f+__expf(-x)); }

__global__ __launch_bounds__(256) void zero_kernel(float* __restrict__ p, int n){
  int i = blockIdx.x*256 + threadIdx.x;
  if (i < n) p[i] = 0.f;
}

// gi[d][t][n][jj] = sum_e word_emb[docs[n*T+t]][e] * Wih[j][e] + bih[j],  j = d*450+jj
__global__ __launch_bounds__(256) void word_gi_kernel(
    const int* __restrict__ docs, const float* __restrict__ emb,
    const float* __restrict__ Wih, const float* __restrict__ bih,
    float* __restrict__ gi){
  __shared__ float A[16][E_];
  int r0 = blockIdx.x * 16;        // 16 rows share t (16 | 1024)
  int t  = r0 >> 10;
  int nb = r0 & 1023;
  for (int idx = threadIdx.x; idx < 16*E_; idx += 256){
    int row = idx / E_, e = idx - row*E_;
    int tok = docs[(nb+row)*T_ + t];
    A[row][e] = emb[(size_t)tok*E_ + e];
  }
  __syncthreads();
  for (int j = threadIdx.x; j < 900; j += 256){
    const float4* wrow = (const float4*)(Wih + (size_t)j*E_);
    float acc[16];
#pragma unroll
    for (int i=0;i<16;i++) acc[i]=0.f;
    for (int e4=0; e4<E_/4; e4++){
      float4 w = wrow[e4];
      int e = e4*4;
#pragma unroll
      for (int i=0;i<16;i++)
        acc[i] += w.x*A[i][e] + w.y*A[i][e+1] + w.z*A[i][e+2] + w.w*A[i][e+3];
    }
    float b = bih[j];
    int d = j/450, jj = j - d*450;
    float* o = gi + ((size_t)(d*T_ + t)*NW_ + nb)*450 + jj;
#pragma unroll
    for (int i=0;i<16;i++) o[(size_t)i*450] = acc[i] + b;
  }
}

// sentence-level gi: rows r = s*64+b, input row = sent_vec[(b*16+s)]
__global__ __launch_bounds__(256) void sent_gi_kernel(
    const float* __restrict__ sv, const float* __restrict__ Wih,
    const float* __restrict__ bih, float* __restrict__ gi){
  __shared__ float A[16][G_];
  int r0 = blockIdx.x * 16;        // 16 rows share s (16 | 64)
  int s  = r0 >> 6;
  int bb = r0 & 63;
  for (int idx = threadIdx.x; idx < 16*G_; idx += 256){
    int row = idx / G_, e = idx - row*G_;
    A[row][e] = sv[((size_t)(bb+row)*S_ + s)*G_ + e];
  }
  __syncthreads();
  for (int j = threadIdx.x; j < 900; j += 256){
    const float4* wrow = (const float4*)(Wih + (size_t)j*G_);
    float acc[16];
#pragma unroll
    for (int i=0;i<16;i++) acc[i]=0.f;
    for (int e4=0; e4<G_/4; e4++){
      float4 w = wrow[e4];
      int e = e4*4;
#pragma unroll
      for (int i=0;i<16;i++)
        acc[i] += w.x*A[i][e] + w.y*A[i][e+1] + w.z*A[i][e+2] + w.w*A[i][e+3];
    }
    float b = bih[j];
    int d = j/450, jj = j - d*450;
    float* o = gi + ((size_t)(d*S_ + s)*B_ + bb)*450 + jj;
#pragma unroll
    for (int i=0;i<16;i++) o[(size_t)i*450] = acc[i] + b;
  }
}

// one GRU time step, both directions (blockIdx.y=d), 8 batch rows per block
__global__ __launch_bounds__(256) void gru_step_kernel(
    const float* __restrict__ gi, const float* __restrict__ Whh,
    const float* __restrict__ bhh, float* __restrict__ hbuf,
    float* __restrict__ hs, int T, int N, int step){
  int d = blockIdx.y;
  int t = (d == 0) ? step : (T-1-step);
  int n0 = blockIdx.x * 8;
  __shared__ float hl[8][H_];
  __shared__ float gh[8][450];
  for (int idx = threadIdx.x; idx < 8*H_; idx += 256){
    int i = idx / H_, e = idx - i*H_;
    hl[i][e] = hbuf[((size_t)d*N + n0 + i)*H_ + e];
  }
  __syncthreads();
  const float* wb = Whh + (size_t)d*450*H_;
  for (int j = threadIdx.x; j < 450; j += 256){
    const float2* wrow = (const float2*)(wb + (size_t)j*H_);
    float acc[8];
#pragma unroll
    for (int i=0;i<8;i++) acc[i]=0.f;
    for (int e2=0; e2<H_/2; e2++){
      float2 w = wrow[e2];
      int e = e2*2;
#pragma unroll
      for (int i=0;i<8;i++) acc[i] += w.x*hl[i][e] + w.y*hl[i][e+1];
    }
    float b = bhh[d*450 + j];
#pragma unroll
    for (int i=0;i<8;i++) gh[i][j] = acc[i] + b;
  }
  __syncthreads();
  const float* gib = gi + ((size_t)(d*T + t)*N + n0)*450;
  for (int idx = threadIdx.x; idx < 8*H_; idx += 256){
    int i = idx / H_, hh = idx - i*H_;
    float ir = gib[(size_t)i*450 + hh];
    float iz = gib[(size_t)i*450 + 150 + hh];
    float in = gib[(size_t)i*450 + 300 + hh];
    float r  = sigm(ir + gh[i][hh]);
    float z  = sigm(iz + gh[i][150+hh]);
    float nn = tanhf(in + r*gh[i][300+hh]);
    float h2 = (1.f - z)*nn + z*hl[i][hh];
    hbuf[((size_t)d*N + n0 + i)*H_ + hh] = h2;
    hs[((size_t)t*N + n0 + i)*G_ + d*H_ + hh] = h2;
  }
}

// score[r] = ctx . tanh(hs[r] @ W^T + b), rows r flattened (t*N+n), 16 rows/block
__global__ __launch_bounds__(256) void att_score_kernel(
    const float* __restrict__ hs, const float* __restrict__ W,
    const float* __restrict__ bias, const float* __restrict__ ctx,
    float* __restrict__ score){
  __shared__ float A[16][G_];
  __shared__ float red[16][4];
  int r0 = blockIdx.x * 16;
  for (int idx = threadIdx.x; idx < 16*G_; idx += 256){
    int row = idx / G_, e = idx - row*G_;
    A[row][e] = hs[(size_t)(r0+row)*G_ + e];
  }
  __syncthreads();
  float part[16];
#pragma unroll
  for (int i=0;i<16;i++) part[i]=0.f;
  for (int h = threadIdx.x; h < G_; h += 256){
    const float4* wrow = (const float4*)(W + (size_t)h*G_);
    float acc[16];
#pragma unroll
    for (int i=0;i<16;i++) acc[i]=0.f;
    for (int e4=0; e4<G_/4; e4++){
      float4 w = wrow[e4];
      int e = e4*4;
#pragma unroll
      for (int i=0;i<16;i++)
        acc[i] += w.x*A[i][e] + w.y*A[i][e+1] + w.z*A[i][e+2] + w.w*A[i][e+3];
    }
    float bb = bias[h], cx = ctx[h];
#pragma unroll
    for (int i=0;i<16;i++) part[i] += cx * tanhf(acc[i] + bb);
  }
  int lane = threadIdx.x & 63, wid = threadIdx.x >> 6;
#pragma unroll
  for (int i=0;i<16;i++){
    float v = part[i];
    for (int off=32; off; off>>=1) v += __shfl_xor(v, off);
    if (lane == 0) red[i][wid] = v;
  }
  __syncthreads();
  if (threadIdx.x < 16)
    score[r0 + threadIdx.x] = red[threadIdx.x][0] + red[threadIdx.x][1]
                            + red[threadIdx.x][2] + red[threadIdx.x][3];
}

// softmax over t (per n) + weighted sum: out[n][g] = sum_t a_t * hs[t][n][g]
__global__ __launch_bounds__(256) void att_combine_kernel(
    const float* __restrict__ score, const float* __restrict__ hs,
    float* __restrict__ out, int T, int N){
  int n = blockIdx.x;
  __shared__ float sa[64];
  if (threadIdx.x < T) sa[threadIdx.x] = score[threadIdx.x*N + n];
  __syncthreads();
  float m = -1e30f;
  for (int t=0;t<T;t++) m = fmaxf(m, sa[t]);
  float den = 0.f;
  for (int t=0;t<T;t++) den += __expf(sa[t]-m);
  float inv = 1.f/den;
  for (int g = threadIdx.x; g < G_; g += 256){
    float acc = 0.f;
    for (int t=0;t<T;t++) acc += __expf(sa[t]-m) * hs[((size_t)t*N+n)*G_ + g];
    out[(size_t)n*G_ + g] = acc * inv;
  }
}

// one warp per (b,k): both cosine sims
__global__ __launch_bounds__(256) void cossim_kernel(
    const int* __restrict__ cand, const int* __restrict__ sens,
    const float* __restrict__ ent, const float* __restrict__ sv,
    const float* __restrict__ odoc, float* __restrict__ sim){
  int w = (blockIdx.x*256 + threadIdx.x) >> 6;
  int lane = threadIdx.x & 63;
  if (w >= B_*NC_) return;
  int b = w / NC_, k = w - b*NC_;
  const float* c  = ent + (size_t)cand[b*NC_ + k]*E_;
  const float* a1 = sv  + ((size_t)b*S_ + sens[b])*G_;
  const float* a2 = odoc + (size_t)b*G_;
  float d1=0.f,d2=0.f,cc=0.f,n1=0.f,n2=0.f;
  for (int e = lane; e < E_; e += 64){
    float cv=c[e], v1=a1[e], v2=a2[e];
    d1+=v1*cv; d2+=v2*cv; cc+=cv*cv; n1+=v1*v1; n2+=v2*v2;
  }
  for (int off=32; off; off>>=1){
    d1+=__shfl_xor(d1,off); d2+=__shfl_xor(d2,off); cc+=__shfl_xor(cc,off);
    n1+=__shfl_xor(n1,off); n2+=__shfl_xor(n2,off);
  }
  if (lane == 0){
    float nc = sqrtf(cc);
    sim[(size_t)b*600 + k]       = d1 / fmaxf(sqrtf(n1)*nc, 1e-8f);
    sim[(size_t)b*600 + 300 + k] = d2 / fmaxf(sqrtf(n2)*nc, 1e-8f);
  }
}

// score = sim @ linW^T + linb; gold gather; argmax (first-max tie rule)
__global__ __launch_bounds__(256) void final_kernel(
    const float* __restrict__ sim, const float* __restrict__ linW,
    const float* __restrict__ linb, const int* __restrict__ idx,
    float* __restrict__ out){
  int b = blockIdx.x;
  __shared__ float ss[600];
  __shared__ float sc[300];
  __shared__ float bv[256];
  __shared__ int   bi[256];
  for (int j = threadIdx.x; j < 600; j += 256) ss[j] = sim[(size_t)b*600 + j];
  __syncthreads();
  float bestv = -1e30f; int besti = 0;
  for (int i = threadIdx.x; i < 300; i += 256){
    const float4* wr = (const float4*)(linW + (size_t)i*600);
    float acc = linb[i];
    for (int j4=0; j4<150; j4++){
      float4 w = wr[j4];
      int j = j4*4;
      acc += w.x*ss[j] + w.y*ss[j+1] + w.z*ss[j+2] + w.w*ss[j+3];
    }
    sc[i] = acc;
    out[64 + (size_t)b*300 + i] = acc;
    if (acc > bestv){ bestv = acc; besti = i; }   // ascending i keeps first max
  }
  bv[threadIdx.x] = bestv; bi[threadIdx.x] = besti;
  __syncthreads();
  for (int s=128; s; s>>=1){
    if (threadIdx.x < s){
      float ov = bv[threadIdx.x+s]; int oi = bi[threadIdx.x+s];
      if (ov > bv[threadIdx.x] || (ov == bv[threadIdx.x] && oi < bi[threadIdx.x])){
        bv[threadIdx.x] = ov; bi[threadIdx.x] = oi;
      }
    }
    __syncthreads();
  }
  if (threadIdx.x == 0){
    out[b] = sc[idx[b]-1];
    out[64 + 64*300 + b] = (float)bi[0];
  }
}

extern "C" void kernel_launch(void* const* d_in, const int* in_sizes, int n_in,
                              void* d_out, int out_size, void* d_ws, size_t ws_size,
                              hipStream_t stream){
  const int*   docs  = (const int*)d_in[0];
  const int*   sens  = (const int*)d_in[1];
  const int*   cand  = (const int*)d_in[2];
  const int*   idx   = (const int*)d_in[3];
  const float* wemb  = (const float*)d_in[4];
  const float* eemb  = (const float*)d_in[5];
  const float* Wih_w = (const float*)d_in[6];
  const float* Whh_w = (const float*)d_in[7];
  const float* bih_w = (const float*)d_in[8];
  const float* bhh_w = (const float*)d_in[9];
  const float* attW_w= (const float*)d_in[10];
  const float* attb_w= (const float*)d_in[11];
  const float* ctx_w = (const float*)d_in[12];
  const float* Wih_s = (const float*)d_in[13];
  const float* Whh_s = (const float*)d_in[14];
  const float* bih_s = (const float*)d_in[15];
  const float* bhh_s = (const float*)d_in[16];
  const float* attW_s= (const float*)d_in[17];
  const float* attb_s= (const float*)d_in[18];
  const float* ctx_s = (const float*)d_in[19];
  const float* linW  = (const float*)d_in[20];
  const float* linb  = (const float*)d_in[21];

  float* ws = (float*)d_ws;
  size_t off = 0;
  float* gi_w    = ws + off; off += (size_t)2*T_*NW_*450;   // 176.9 MB
  float* hbuf_w  = ws + off; off += (size_t)2*NW_*H_;
  float* hs_w    = ws + off; off += (size_t)T_*NW_*G_;      // 59 MB
  float* score_w = ws + off; off += (size_t)T_*NW_;
  float* sv      = ws + off; off += (size_t)NW_*G_;
  float* gi_s    = ws + off; off += (size_t)2*S_*B_*450;
  float* hbuf_s  = ws + off; off += (size_t)2*B_*H_;
  float* hs_s    = ws + off; off += (size_t)S_*B_*G_;
  float* score_s = ws + off; off += (size_t)S_*B_;
  float* odoc    = ws + off; off += (size_t)B_*G_;
  float* sim     = ws + off; off += (size_t)B_*600;

  float* out = (float*)d_out;

  // zero recurrent states
  zero_kernel<<<(2*NW_*H_ + 255)/256, 256, 0, stream>>>(hbuf_w, 2*NW_*H_);
  zero_kernel<<<(2*B_*H_  + 255)/256, 256, 0, stream>>>(hbuf_s, 2*B_*H_);

  // word level
  word_gi_kernel<<<RW_/16, 256, 0, stream>>>(docs, wemb, Wih_w, bih_w, gi_w);
  for (int s = 0; s < T_; ++s)
    gru_step_kernel<<<dim3(NW_/8, 2), 256, 0, stream>>>(gi_w, Whh_w, bhh_w,
                                                        hbuf_w, hs_w, T_, NW_, s);
  att_score_kernel<<<RW_/16, 256, 0, stream>>>(hs_w, attW_w, attb_w, ctx_w, score_w);
  att_combine_kernel<<<NW_, 256, 0, stream>>>(score_w, hs_w, sv, T_, NW_);

  // sentence level
  sent_gi_kernel<<<RS_/16, 256, 0, stream>>>(sv, Wih_s, bih_s, gi_s);
  for (int s = 0; s < S_; ++s)
    gru_step_kernel<<<dim3(B_/8, 2), 256, 0, stream>>>(gi_s, Whh_s, bhh_s,
                                                       hbuf_s, hs_s, S_, B_, s);
  att_score_kernel<<<RS_/16, 256, 0, stream>>>(hs_s, attW_s, attb_s, ctx_s, score_s);
  att_combine_kernel<<<B_, 256, 0, stream>>>(score_s, hs_s, odoc, S_, B_);

  // similarity + linear + gold + argmax
  cossim_kernel<<<(B_*NC_*64)/256, 256, 0, stream>>>(cand, sens, eemb, sv, odoc, sim);
  final_kernel<<<B_, 256, 0, stream>>>(sim, linW, linb, idx, out);
}

// Round 2
// 2404.232 us; speedup vs baseline: 1.2473x; 1.2473x over previous
//
#include <hip/hip_runtime.h>
#include <hip/hip_bf16.h>
#include <math.h>

#define B_  64
#define S_  16
#define T_  48
#define E_  300
#define H_  150
#define G_  300   // 2H
#define NC_ 300
#define NW_ (B_*S_)     // 1024 word-level batch
#define RW_ (T_*NW_)    // 49152 word rows
#define RS_ (S_*B_)     // 1024 sentence rows

__device__ __forceinline__ float sigm(float x){ return 1.0f/(1.0f+__expf(-x)); }

// ---------------------------------------------------------------------------
// gi[t][n][j] (j in [0,900), 900 per row) = emb[docs[n,t]] @ Wih^T + bih
// 16 rows/block, thread = 4 consecutive j columns (225 active of 256)
// ---------------------------------------------------------------------------
__global__ __launch_bounds__(256) void word_gi_kernel(
    const int* __restrict__ docs, const float* __restrict__ emb,
    const float* __restrict__ Wih, const float* __restrict__ bih,
    float* __restrict__ gi){
  __shared__ float A[16][E_];
  int r0 = blockIdx.x * 16;
  int t  = r0 >> 10;
  int nb = r0 & 1023;
  for (int idx = threadIdx.x; idx < 16*75; idx += 256){
    int row = idx / 75, e4 = idx - row*75;
    int tok = docs[(nb+row)*T_ + t];
    *(float4*)&A[row][e4*4] = *(const float4*)&emb[(size_t)tok*E_ + e4*4];
  }
  __syncthreads();
  int q = threadIdx.x;
  if (q >= 225) return;
  int j0 = q*4;
  const float4* w0 = (const float4*)(Wih + (size_t)(j0  )*E_);
  const float4* w1 = (const float4*)(Wih + (size_t)(j0+1)*E_);
  const float4* w2 = (const float4*)(Wih + (size_t)(j0+2)*E_);
  const float4* w3 = (const float4*)(Wih + (size_t)(j0+3)*E_);
  float acc[16][4];
#pragma unroll
  for (int i=0;i<16;i++){ acc[i][0]=0.f; acc[i][1]=0.f; acc[i][2]=0.f; acc[i][3]=0.f; }
  for (int e4=0; e4<75; e4++){
    float4 b0=w0[e4], b1=w1[e4], b2=w2[e4], b3=w3[e4];
#pragma unroll
    for (int i=0;i<16;i++){
      float4 av = *(const float4*)&A[i][e4*4];
      acc[i][0] += av.x*b0.x + av.y*b0.y + av.z*b0.z + av.w*b0.w;
      acc[i][1] += av.x*b1.x + av.y*b1.y + av.z*b1.z + av.w*b1.w;
      acc[i][2] += av.x*b2.x + av.y*b2.y + av.z*b2.z + av.w*b2.w;
      acc[i][3] += av.x*b3.x + av.y*b3.y + av.z*b3.z + av.w*b3.w;
    }
  }
  float4 bb = *(const float4*)&bih[j0];
#pragma unroll
  for (int i=0;i<16;i++){
    float4 o4;
    o4.x = acc[i][0]+bb.x; o4.y = acc[i][1]+bb.y;
    o4.z = acc[i][2]+bb.z; o4.w = acc[i][3]+bb.w;
    *(float4*)&gi[((size_t)(t*NW_) + nb + i)*900 + j0] = o4;
  }
}

// sentence-level gi: rows r = s*64+b, input row = sv[(b*16+s)]
__global__ __launch_bounds__(256) void sent_gi_kernel(
    const float* __restrict__ sv, const float* __restrict__ Wih,
    const float* __restrict__ bih, float* __restrict__ gi){
  __shared__ float A[16][G_];
  int r0 = blockIdx.x * 16;
  int s  = r0 >> 6;
  int bb_ = r0 & 63;
  for (int idx = threadIdx.x; idx < 16*75; idx += 256){
    int row = idx / 75, e4 = idx - row*75;
    *(float4*)&A[row][e4*4] =
        *(const float4*)&sv[(((size_t)(bb_+row))*S_ + s)*G_ + e4*4];
  }
  __syncthreads();
  int q = threadIdx.x;
  if (q >= 225) return;
  int j0 = q*4;
  const float4* w0 = (const float4*)(Wih + (size_t)(j0  )*G_);
  const float4* w1 = (const float4*)(Wih + (size_t)(j0+1)*G_);
  const float4* w2 = (const float4*)(Wih + (size_t)(j0+2)*G_);
  const float4* w3 = (const float4*)(Wih + (size_t)(j0+3)*G_);
  float acc[16][4];
#pragma unroll
  for (int i=0;i<16;i++){ acc[i][0]=0.f; acc[i][1]=0.f; acc[i][2]=0.f; acc[i][3]=0.f; }
  for (int e4=0; e4<75; e4++){
    float4 b0=w0[e4], b1=w1[e4], b2=w2[e4], b3=w3[e4];
#pragma unroll
    for (int i=0;i<16;i++){
      float4 av = *(const float4*)&A[i][e4*4];
      acc[i][0] += av.x*b0.x + av.y*b0.y + av.z*b0.z + av.w*b0.w;
      acc[i][1] += av.x*b1.x + av.y*b1.y + av.z*b1.z + av.w*b1.w;
      acc[i][2] += av.x*b2.x + av.y*b2.y + av.z*b2.z + av.w*b2.w;
      acc[i][3] += av.x*b3.x + av.y*b3.y + av.z*b3.z + av.w*b3.w;
    }
  }
  float4 bb = *(const float4*)&bih[j0];
#pragma unroll
  for (int i=0;i<16;i++){
    float4 o4;
    o4.x = acc[i][0]+bb.x; o4.y = acc[i][1]+bb.y;
    o4.z = acc[i][2]+bb.z; o4.w = acc[i][3]+bb.w;
    *(float4*)&gi[((size_t)(s*B_) + bb_ + i)*900 + j0] = o4;
  }
}

// ---------------------------------------------------------------------------
// Persistent GRU scan: block = (8 rows, 1 direction), loops all T steps.
// h lives in LDS; Whh read from L2 each step; gh via 8row x 2col reg tiles.
// ---------------------------------------------------------------------------
__global__ __launch_bounds__(256) void gru_scan_kernel(
    const float* __restrict__ gi, const float* __restrict__ Whh,
    const float* __restrict__ bhh, float* __restrict__ hs,
    int T, int N){
  int d  = blockIdx.y;
  int n0 = blockIdx.x * 8;
  __shared__ float hl[8][H_];
  __shared__ float gh[8][452];
  for (int idx = threadIdx.x; idx < 8*H_; idx += 256)
    hl[idx/H_][idx%H_] = 0.f;
  __syncthreads();
  int q  = threadIdx.x;
  int j0 = q*2;
  const float2* w0 = nullptr; const float2* w1 = nullptr;
  float b0 = 0.f, b1 = 0.f;
  if (q < 225){
    const float* wb = Whh + (size_t)d*450*H_;
    w0 = (const float2*)(wb + (size_t)(j0  )*H_);
    w1 = (const float2*)(wb + (size_t)(j0+1)*H_);
    b0 = bhh[d*450 + j0]; b1 = bhh[d*450 + j0 + 1];
  }
  for (int step=0; step<T; ++step){
    int t = d ? (T-1-step) : step;
    if (q < 225){
      float a0[8], a1[8];
#pragma unroll
      for (int i=0;i<8;i++){ a0[i]=0.f; a1[i]=0.f; }
#pragma unroll 5
      for (int e2=0; e2<75; e2++){
        float2 x0 = w0[e2], x1 = w1[e2];
#pragma unroll
        for (int i=0;i<8;i++){
          float2 hh = *(const float2*)&hl[i][e2*2];
          a0[i] += x0.x*hh.x + x0.y*hh.y;
          a1[i] += x1.x*hh.x + x1.y*hh.y;
        }
      }
#pragma unroll
      for (int i=0;i<8;i++){
        float2 g2; g2.x = a0[i]+b0; g2.y = a1[i]+b1;
        *(float2*)&gh[i][j0] = g2;
      }
    }
    __syncthreads();
    const float* gib = gi + ((size_t)t*N + n0)*900 + d*450;
    for (int idx = threadIdx.x; idx < 8*H_; idx += 256){
      int i = idx/H_, h = idx - i*H_;
      float ir = gib[(size_t)i*900 + h];
      float iz = gib[(size_t)i*900 + 150 + h];
      float in = gib[(size_t)i*900 + 300 + h];
      float r  = sigm(ir + gh[i][h]);
      float z  = sigm(iz + gh[i][150+h]);
      float nn = tanhf(in + r*gh[i][300+h]);
      float h2 = (1.f - z)*nn + z*hl[i][h];
      hl[i][h] = h2;
      hs[((size_t)t*N + n0 + i)*G_ + d*H_ + h] = h2;
    }
    __syncthreads();
  }
}

// ---------------------------------------------------------------------------
// score[r] = ctx . tanh(hs[r] @ W^T + b); 48 rows/block,
// thread = (rg in 0..2)*16 rows x 4 cols; reduction reuses A.
// ---------------------------------------------------------------------------
__global__ __launch_bounds__(256) void att_score_kernel(
    const float* __restrict__ hs, const float* __restrict__ W,
    const float* __restrict__ bias, const float* __restrict__ ctx,
    float* __restrict__ score, int Rtot){
  __shared__ float A[48*G_];   // 57.6 KB
  int r0 = blockIdx.x * 48;
  for (int idx = threadIdx.x; idx < 48*75; idx += 256){
    int row = idx / 75, e4 = idx - row*75;
    float4 v;
    if (r0 + row < Rtot) v = *(const float4*)&hs[(size_t)(r0+row)*G_ + e4*4];
    else { v.x=0.f; v.y=0.f; v.z=0.f; v.w=0.f; }
    *(float4*)&A[row*G_ + e4*4] = v;
  }
  __syncthreads();
  int tid = threadIdx.x;
  int rg = tid / 75, q = tid - rg*75;
  float part[16];
#pragma unroll
  for (int i=0;i<16;i++) part[i]=0.f;
  if (tid < 225){
    int h0 = q*4;
    const float4* w0 = (const float4*)(W + (size_t)(h0  )*G_);
    const float4* w1 = (const float4*)(W + (size_t)(h0+1)*G_);
    const float4* w2 = (const float4*)(W + (size_t)(h0+2)*G_);
    const float4* w3 = (const float4*)(W + (size_t)(h0+3)*G_);
    float acc[16][4];
#pragma unroll
    for (int i=0;i<16;i++){ acc[i][0]=0.f; acc[i][1]=0.f; acc[i][2]=0.f; acc[i][3]=0.f; }
    const float* Ab = &A[(size_t)rg*16*G_];
    for (int e4=0; e4<75; e4++){
      float4 b0=w0[e4], b1=w1[e4], b2=w2[e4], b3=w3[e4];
#pragma unroll
      for (int i=0;i<16;i++){
        float4 av = *(const float4*)&Ab[(size_t)i*G_ + e4*4];
        acc[i][0] += av.x*b0.x + av.y*b0.y + av.z*b0.z + av.w*b0.w;
        acc[i][1] += av.x*b1.x + av.y*b1.y + av.z*b1.z + av.w*b1.w;
        acc[i][2] += av.x*b2.x + av.y*b2.y + av.z*b2.z + av.w*b2.w;
        acc[i][3] += av.x*b3.x + av.y*b3.y + av.z*b3.z + av.w*b3.w;
      }
    }
    float4 bb = *(const float4*)&bias[h0];
    float4 cx = *(const float4*)&ctx[h0];
#pragma unroll
    for (int i=0;i<16;i++){
      part[i] = cx.x*tanhf(acc[i][0]+bb.x) + cx.y*tanhf(acc[i][1]+bb.y)
              + cx.z*tanhf(acc[i][2]+bb.z) + cx.w*tanhf(acc[i][3]+bb.w);
    }
  }
  __syncthreads();       // done reading A
  if (tid < 225){
#pragma unroll
    for (int i=0;i<16;i++) A[q*48 + rg*16 + i] = part[i];
  }
  __syncthreads();
  if (tid < 48 && r0 + tid < Rtot){
    float s = 0.f;
    for (int q2=0; q2<75; q2++) s += A[q2*48 + tid];
    score[r0 + tid] = s;
  }
}

// softmax over t (per n) + weighted sum
__global__ __launch_bounds__(256) void att_combine_kernel(
    const float* __restrict__ score, const float* __restrict__ hs,
    float* __restrict__ out, int T, int N){
  int n = blockIdx.x;
  __shared__ float wa[64];
  if (threadIdx.x < T) wa[threadIdx.x] = score[threadIdx.x*N + n];
  __syncthreads();
  float m = -1e30f;
  for (int t=0;t<T;t++) m = fmaxf(m, wa[t]);
  float den = 0.f;
  for (int t=0;t<T;t++) den += __expf(wa[t]-m);
  float inv = 1.f/den;
  __syncthreads();
  if (threadIdx.x < T) wa[threadIdx.x] = __expf(wa[threadIdx.x]-m)*inv;
  __syncthreads();
  for (int g = threadIdx.x; g < G_; g += 256){
    float acc = 0.f;
    for (int t=0;t<T;t++) acc += wa[t] * hs[((size_t)t*N+n)*G_ + g];
    out[(size_t)n*G_ + g] = acc;
  }
}

// one wave per (b,k): both cosine sims
__global__ __launch_bounds__(256) void cossim_kernel(
    const int* __restrict__ cand, const int* __restrict__ sens,
    const float* __restrict__ ent, const float* __restrict__ sv,
    const float* __restrict__ odoc, float* __restrict__ sim){
  int w = (blockIdx.x*256 + threadIdx.x) >> 6;
  int lane = threadIdx.x & 63;
  if (w >= B_*NC_) return;
  int b = w / NC_, k = w - b*NC_;
  const float* c  = ent + (size_t)cand[b*NC_ + k]*E_;
  const float* a1 = sv  + ((size_t)b*S_ + sens[b])*G_;
  const float* a2 = odoc + (size_t)b*G_;
  float d1=0.f,d2=0.f,cc=0.f,n1=0.f,n2=0.f;
  for (int e = lane; e < E_; e += 64){
    float cv=c[e], v1=a1[e], v2=a2[e];
    d1+=v1*cv; d2+=v2*cv; cc+=cv*cv; n1+=v1*v1; n2+=v2*v2;
  }
  for (int off=32; off; off>>=1){
    d1+=__shfl_xor(d1,off); d2+=__shfl_xor(d2,off); cc+=__shfl_xor(cc,off);
    n1+=__shfl_xor(n1,off); n2+=__shfl_xor(n2,off);
  }
  if (lane == 0){
    float nc = sqrtf(cc);
    sim[(size_t)b*600 + k]       = d1 / fmaxf(sqrtf(n1)*nc, 1e-8f);
    sim[(size_t)b*600 + 300 + k] = d2 / fmaxf(sqrtf(n2)*nc, 1e-8f);
  }
}

// score = sim @ linW^T + linb; gold gather; argmax (first-max tie rule)
__global__ __launch_bounds__(256) void final_kernel(
    const float* __restrict__ sim, const float* __restrict__ linW,
    const float* __restrict__ linb, const int* __restrict__ idx,
    float* __restrict__ out){
  int b = blockIdx.x;
  __shared__ float ss[600];
  __shared__ float sc[300];
  __shared__ float bv[256];
  __shared__ int   bi[256];
  for (int j = threadIdx.x; j < 600; j += 256) ss[j] = sim[(size_t)b*600 + j];
  __syncthreads();
  float bestv = -1e30f; int besti = 0;
  for (int i = threadIdx.x; i < 300; i += 256){
    const float4* wr = (const float4*)(linW + (size_t)i*600);
    float acc = linb[i];
    for (int j4=0; j4<150; j4++){
      float4 w = wr[j4];
      int j = j4*4;
      acc += w.x*ss[j] + w.y*ss[j+1] + w.z*ss[j+2] + w.w*ss[j+3];
    }
    sc[i] = acc;
    out[64 + (size_t)b*300 + i] = acc;
    if (acc > bestv){ bestv = acc; besti = i; }
  }
  bv[threadIdx.x] = bestv; bi[threadIdx.x] = besti;
  __syncthreads();
  for (int s=128; s; s>>=1){
    if (threadIdx.x < s){
      float ov = bv[threadIdx.x+s]; int oi = bi[threadIdx.x+s];
      if (ov > bv[threadIdx.x] || (ov == bv[threadIdx.x] && oi < bi[threadIdx.x])){
        bv[threadIdx.x] = ov; bi[threadIdx.x] = oi;
      }
    }
    __syncthreads();
  }
  if (threadIdx.x == 0){
    out[b] = sc[idx[b]-1];
    out[64 + 64*300 + b] = (float)bi[0];
  }
}

extern "C" void kernel_launch(void* const* d_in, const int* in_sizes, int n_in,
                              void* d_out, int out_size, void* d_ws, size_t ws_size,
                              hipStream_t stream){
  const int*   docs  = (const int*)d_in[0];
  const int*   sens  = (const int*)d_in[1];
  const int*   cand  = (const int*)d_in[2];
  const int*   idx   = (const int*)d_in[3];
  const float* wemb  = (const float*)d_in[4];
  const float* eemb  = (const float*)d_in[5];
  const float* Wih_w = (const float*)d_in[6];
  const float* Whh_w = (const float*)d_in[7];
  const float* bih_w = (const float*)d_in[8];
  const float* bhh_w = (const float*)d_in[9];
  const float* attW_w= (const float*)d_in[10];
  const float* attb_w= (const float*)d_in[11];
  const float* ctx_w = (const float*)d_in[12];
  const float* Wih_s = (const float*)d_in[13];
  const float* Whh_s = (const float*)d_in[14];
  const float* bih_s = (const float*)d_in[15];
  const float* bhh_s = (const float*)d_in[16];
  const float* attW_s= (const float*)d_in[17];
  const float* attb_s= (const float*)d_in[18];
  const float* ctx_s = (const float*)d_in[19];
  const float* linW  = (const float*)d_in[20];
  const float* linb  = (const float*)d_in[21];

  float* ws = (float*)d_ws;
  size_t off = 0;
  float* gi_w    = ws + off; off += (size_t)T_*NW_*900;   // 176.9 MB
  float* hs_w    = ws + off; off += (size_t)T_*NW_*G_;    // 59 MB
  float* score_w = ws + off; off += (size_t)T_*NW_;
  float* sv      = ws + off; off += (size_t)NW_*G_;
  float* gi_s    = ws + off; off += (size_t)S_*B_*900;
  float* hs_s    = ws + off; off += (size_t)S_*B_*G_;
  float* score_s = ws + off; off += (size_t)S_*B_;
  float* odoc    = ws + off; off += (size_t)B_*G_;
  float* sim     = ws + off; off += (size_t)B_*600;

  float* out = (float*)d_out;

  // word level
  word_gi_kernel<<<RW_/16, 256, 0, stream>>>(docs, wemb, Wih_w, bih_w, gi_w);
  gru_scan_kernel<<<dim3(NW_/8, 2), 256, 0, stream>>>(gi_w, Whh_w, bhh_w,
                                                      hs_w, T_, NW_);
  att_score_kernel<<<(RW_+47)/48, 256, 0, stream>>>(hs_w, attW_w, attb_w,
                                                    ctx_w, score_w, RW_);
  att_combine_kernel<<<NW_, 256, 0, stream>>>(score_w, hs_w, sv, T_, NW_);

  // sentence level
  sent_gi_kernel<<<RS_/16, 256, 0, stream>>>(sv, Wih_s, bih_s, gi_s);
  gru_scan_kernel<<<dim3(B_/8, 2), 256, 0, stream>>>(gi_s, Whh_s, bhh_s,
                                                     hs_s, S_, B_);
  att_score_kernel<<<(RS_+47)/48, 256, 0, stream>>>(hs_s, attW_s, attb_s,
                                                    ctx_s, score_s, RS_);
  att_combine_kernel<<<B_, 256, 0, stream>>>(score_s, hs_s, odoc, S_, B_);

  // similarity + linear + gold + argmax
  cossim_kernel<<<(B_*NC_*64)/256, 256, 0, stream>>>(cand, sens, eemb, sv, odoc, sim);
  final_kernel<<<B_, 256, 0, stream>>>(sim, linW, linb, idx, out);
}

// Round 3
// 1976.235 us; speedup vs baseline: 1.5174x; 1.2166x over previous
//
#include <hip/hip_runtime.h>
#include <hip/hip_bf16.h>
#include <math.h>

#define B_  64
#define S_  16
#define T_  48
#define E_  300
#define H_  150
#define G_  300   // 2H
#define NC_ 300
#define NW_ (B_*S_)     // 1024 word-level batch
#define RW_ (T_*NW_)    // 49152 word rows
#define RS_ (S_*B_)     // 1024 sentence rows

__device__ __forceinline__ float sigm(float x){ return 1.0f/(1.0f+__expf(-x)); }

// ---------------------------------------------------------------------------
// gi[t][n][j] (j in [0,900)) = emb[docs[n,t]] @ Wih^T + bih
// 16 rows/block, thread = 4 consecutive j columns (225 active of 256)
// ---------------------------------------------------------------------------
__global__ __launch_bounds__(256) void word_gi_kernel(
    const int* __restrict__ docs, const float* __restrict__ emb,
    const float* __restrict__ Wih, const float* __restrict__ bih,
    float* __restrict__ gi){
  __shared__ float A[16][E_];
  int r0 = blockIdx.x * 16;
  int t  = r0 >> 10;
  int nb = r0 & 1023;
  for (int idx = threadIdx.x; idx < 16*75; idx += 256){
    int row = idx / 75, e4 = idx - row*75;
    int tok = docs[(nb+row)*T_ + t];
    *(float4*)&A[row][e4*4] = *(const float4*)&emb[(size_t)tok*E_ + e4*4];
  }
  __syncthreads();
  int q = threadIdx.x;
  if (q >= 225) return;
  int j0 = q*4;
  const float4* w0 = (const float4*)(Wih + (size_t)(j0  )*E_);
  const float4* w1 = (const float4*)(Wih + (size_t)(j0+1)*E_);
  const float4* w2 = (const float4*)(Wih + (size_t)(j0+2)*E_);
  const float4* w3 = (const float4*)(Wih + (size_t)(j0+3)*E_);
  float acc[16][4];
#pragma unroll
  for (int i=0;i<16;i++){ acc[i][0]=0.f; acc[i][1]=0.f; acc[i][2]=0.f; acc[i][3]=0.f; }
  for (int e4=0; e4<75; e4++){
    float4 b0=w0[e4], b1=w1[e4], b2=w2[e4], b3=w3[e4];
#pragma unroll
    for (int i=0;i<16;i++){
      float4 av = *(const float4*)&A[i][e4*4];
      acc[i][0] += av.x*b0.x + av.y*b0.y + av.z*b0.z + av.w*b0.w;
      acc[i][1] += av.x*b1.x + av.y*b1.y + av.z*b1.z + av.w*b1.w;
      acc[i][2] += av.x*b2.x + av.y*b2.y + av.z*b2.z + av.w*b2.w;
      acc[i][3] += av.x*b3.x + av.y*b3.y + av.z*b3.z + av.w*b3.w;
    }
  }
  float4 bb = *(const float4*)&bih[j0];
#pragma unroll
  for (int i=0;i<16;i++){
    float4 o4;
    o4.x = acc[i][0]+bb.x; o4.y = acc[i][1]+bb.y;
    o4.z = acc[i][2]+bb.z; o4.w = acc[i][3]+bb.w;
    *(float4*)&gi[((size_t)(t*NW_) + nb + i)*900 + j0] = o4;
  }
}

// sentence-level gi: rows r = s*64+b, input row = sv[(b*16+s)]
__global__ __launch_bounds__(256) void sent_gi_kernel(
    const float* __restrict__ sv, const float* __restrict__ Wih,
    const float* __restrict__ bih, float* __restrict__ gi){
  __shared__ float A[16][G_];
  int r0 = blockIdx.x * 16;
  int s  = r0 >> 6;
  int bb_ = r0 & 63;
  for (int idx = threadIdx.x; idx < 16*75; idx += 256){
    int row = idx / 75, e4 = idx - row*75;
    *(float4*)&A[row][e4*4] =
        *(const float4*)&sv[(((size_t)(bb_+row))*S_ + s)*G_ + e4*4];
  }
  __syncthreads();
  int q = threadIdx.x;
  if (q >= 225) return;
  int j0 = q*4;
  const float4* w0 = (const float4*)(Wih + (size_t)(j0  )*G_);
  const float4* w1 = (const float4*)(Wih + (size_t)(j0+1)*G_);
  const float4* w2 = (const float4*)(Wih + (size_t)(j0+2)*G_);
  const float4* w3 = (const float4*)(Wih + (size_t)(j0+3)*G_);
  float acc[16][4];
#pragma unroll
  for (int i=0;i<16;i++){ acc[i][0]=0.f; acc[i][1]=0.f; acc[i][2]=0.f; acc[i][3]=0.f; }
  for (int e4=0; e4<75; e4++){
    float4 b0=w0[e4], b1=w1[e4], b2=w2[e4], b3=w3[e4];
#pragma unroll
    for (int i=0;i<16;i++){
      float4 av = *(const float4*)&A[i][e4*4];
      acc[i][0] += av.x*b0.x + av.y*b0.y + av.z*b0.z + av.w*b0.w;
      acc[i][1] += av.x*b1.x + av.y*b1.y + av.z*b1.z + av.w*b1.w;
      acc[i][2] += av.x*b2.x + av.y*b2.y + av.z*b2.z + av.w*b2.w;
      acc[i][3] += av.x*b3.x + av.y*b3.y + av.z*b3.z + av.w*b3.w;
    }
  }
  float4 bb = *(const float4*)&bih[j0];
#pragma unroll
  for (int i=0;i<16;i++){
    float4 o4;
    o4.x = acc[i][0]+bb.x; o4.y = acc[i][1]+bb.y;
    o4.z = acc[i][2]+bb.z; o4.w = acc[i][3]+bb.w;
    *(float4*)&gi[((size_t)(s*B_) + bb_ + i)*900 + j0] = o4;
  }
}

// ---------------------------------------------------------------------------
// Persistent GRU scan: block = (R rows, 1 direction), TPB threads, loops T.
// Thread = 1 Whh column x R rows (450 active); hl broadcast from LDS (float4);
// gi for the elementwise phase prefetched at step start (hides HBM/L3 latency
// under the GEMM).
// ---------------------------------------------------------------------------
template<int R, int TPB>
__global__ __launch_bounds__(TPB) void gru_scan_kernel(
    const float* __restrict__ gi, const float* __restrict__ Whh,
    const float* __restrict__ bhh, float* __restrict__ hs,
    int T, int N){
  constexpr int EW = (R*H_ + TPB - 1)/TPB;
  int d  = blockIdx.y;
  int n0 = blockIdx.x * R;
  __shared__ float hl[R][152];   // row stride 152 floats (16B-aligned rows)
  __shared__ float gh[R][452];
  for (int idx = threadIdx.x; idx < R*H_; idx += TPB)
    hl[idx/H_][idx%H_] = 0.f;
  __syncthreads();
  int q = threadIdx.x;
  const float* wrow = nullptr; float bb = 0.f;
  if (q < 450){
    wrow = Whh + (size_t)d*450*H_ + (size_t)q*H_;
    bb   = bhh[d*450 + q];
  }
  for (int step=0; step<T; ++step){
    int t = d ? (T-1-step) : step;
    const float* gib = gi + ((size_t)t*N + n0)*900 + d*450;
    // prefetch gi needed by this step's elementwise phase
    float pre[EW][3];
#pragma unroll
    for (int u=0; u<EW; ++u){
      int idx = q + u*TPB;
      if (idx < R*H_){
        int i = idx/H_, h = idx - i*H_;
        const float* g0 = gib + (size_t)i*900 + h;
        pre[u][0] = g0[0];
        pre[u][1] = g0[150];
        pre[u][2] = g0[300];
      }
    }
    // GEMM: gh[i][q] = sum_e Whh[q][e]*hl[i][e] + bhh[q]
    if (q < 450){
      float a[R];
#pragma unroll
      for (int i=0;i<R;i++) a[i]=0.f;
      const float4* w4 = (const float4*)wrow;
#pragma unroll 4
      for (int e4=0; e4<37; ++e4){
        float4 wv = w4[e4];
#pragma unroll
        for (int i=0;i<R;i++){
          float4 hv = *(const float4*)&hl[i][e4*4];
          a[i] += wv.x*hv.x + wv.y*hv.y + wv.z*hv.z + wv.w*hv.w;
        }
      }
      float2 wt = *(const float2*)&wrow[148];
#pragma unroll
      for (int i=0;i<R;i++){
        float2 ht = *(const float2*)&hl[i][148];
        a[i] += wt.x*ht.x + wt.y*ht.y;
      }
#pragma unroll
      for (int i=0;i<R;i++) gh[i][q] = a[i] + bb;
    }
    __syncthreads();
    // elementwise GRU update
#pragma unroll
    for (int u=0; u<EW; ++u){
      int idx = q + u*TPB;
      if (idx < R*H_){
        int i = idx/H_, h = idx - i*H_;
        float r  = sigm(pre[u][0] + gh[i][h]);
        float z  = sigm(pre[u][1] + gh[i][150+h]);
        float nn = tanhf(pre[u][2] + r*gh[i][300+h]);
        float h2 = (1.f - z)*nn + z*hl[i][h];
        hl[i][h] = h2;
        hs[((size_t)t*N + n0 + i)*G_ + d*H_ + h] = h2;
      }
    }
    __syncthreads();
  }
}

// ---------------------------------------------------------------------------
// score[r] = ctx . tanh(hs[r] @ W^T + b); 48 rows/block
// ---------------------------------------------------------------------------
__global__ __launch_bounds__(256) void att_score_kernel(
    const float* __restrict__ hs, const float* __restrict__ W,
    const float* __restrict__ bias, const float* __restrict__ ctx,
    float* __restrict__ score, int Rtot){
  __shared__ float A[48*G_];   // 57.6 KB
  int r0 = blockIdx.x * 48;
  for (int idx = threadIdx.x; idx < 48*75; idx += 256){
    int row = idx / 75, e4 = idx - row*75;
    float4 v;
    if (r0 + row < Rtot) v = *(const float4*)&hs[(size_t)(r0+row)*G_ + e4*4];
    else { v.x=0.f; v.y=0.f; v.z=0.f; v.w=0.f; }
    *(float4*)&A[row*G_ + e4*4] = v;
  }
  __syncthreads();
  int tid = threadIdx.x;
  int rg = tid / 75, q = tid - rg*75;
  float part[16];
#pragma unroll
  for (int i=0;i<16;i++) part[i]=0.f;
  if (tid < 225){
    int h0 = q*4;
    const float4* w0 = (const float4*)(W + (size_t)(h0  )*G_);
    const float4* w1 = (const float4*)(W + (size_t)(h0+1)*G_);
    const float4* w2 = (const float4*)(W + (size_t)(h0+2)*G_);
    const float4* w3 = (const float4*)(W + (size_t)(h0+3)*G_);
    float acc[16][4];
#pragma unroll
    for (int i=0;i<16;i++){ acc[i][0]=0.f; acc[i][1]=0.f; acc[i][2]=0.f; acc[i][3]=0.f; }
    const float* Ab = &A[(size_t)rg*16*G_];
    for (int e4=0; e4<75; e4++){
      float4 b0=w0[e4], b1=w1[e4], b2=w2[e4], b3=w3[e4];
#pragma unroll
      for (int i=0;i<16;i++){
        float4 av = *(const float4*)&Ab[(size_t)i*G_ + e4*4];
        acc[i][0] += av.x*b0.x + av.y*b0.y + av.z*b0.z + av.w*b0.w;
        acc[i][1] += av.x*b1.x + av.y*b1.y + av.z*b1.z + av.w*b1.w;
        acc[i][2] += av.x*b2.x + av.y*b2.y + av.z*b2.z + av.w*b2.w;
        acc[i][3] += av.x*b3.x + av.y*b3.y + av.z*b3.z + av.w*b3.w;
      }
    }
    float4 bb = *(const float4*)&bias[h0];
    float4 cx = *(const float4*)&ctx[h0];
#pragma unroll
    for (int i=0;i<16;i++){
      part[i] = cx.x*tanhf(acc[i][0]+bb.x) + cx.y*tanhf(acc[i][1]+bb.y)
              + cx.z*tanhf(acc[i][2]+bb.z) + cx.w*tanhf(acc[i][3]+bb.w);
    }
  }
  __syncthreads();
  if (tid < 225){
#pragma unroll
    for (int i=0;i<16;i++) A[q*48 + rg*16 + i] = part[i];
  }
  __syncthreads();
  if (tid < 48 && r0 + tid < Rtot){
    float s = 0.f;
    for (int q2=0; q2<75; q2++) s += A[q2*48 + tid];
    score[r0 + tid] = s;
  }
}

// softmax over t (per n) + weighted sum
__global__ __launch_bounds__(256) void att_combine_kernel(
    const float* __restrict__ score, const float* __restrict__ hs,
    float* __restrict__ out, int T, int N){
  int n = blockIdx.x;
  __shared__ float wa[64];
  if (threadIdx.x < T) wa[threadIdx.x] = score[threadIdx.x*N + n];
  __syncthreads();
  float m = -1e30f;
  for (int t=0;t<T;t++) m = fmaxf(m, wa[t]);
  float den = 0.f;
  for (int t=0;t<T;t++) den += __expf(wa[t]-m);
  float inv = 1.f/den;
  __syncthreads();
  if (threadIdx.x < T) wa[threadIdx.x] = __expf(wa[threadIdx.x]-m)*inv;
  __syncthreads();
  for (int g = threadIdx.x; g < G_; g += 256){
    float acc = 0.f;
    for (int t=0;t<T;t++) acc += wa[t] * hs[((size_t)t*N+n)*G_ + g];
    out[(size_t)n*G_ + g] = acc;
  }
}

// one wave per (b,k): both cosine sims
__global__ __launch_bounds__(256) void cossim_kernel(
    const int* __restrict__ cand, const int* __restrict__ sens,
    const float* __restrict__ ent, const float* __restrict__ sv,
    const float* __restrict__ odoc, float* __restrict__ sim){
  int w = (blockIdx.x*256 + threadIdx.x) >> 6;
  int lane = threadIdx.x & 63;
  if (w >= B_*NC_) return;
  int b = w / NC_, k = w - b*NC_;
  const float* c  = ent + (size_t)cand[b*NC_ + k]*E_;
  const float* a1 = sv  + ((size_t)b*S_ + sens[b])*G_;
  const float* a2 = odoc + (size_t)b*G_;
  float d1=0.f,d2=0.f,cc=0.f,n1=0.f,n2=0.f;
  for (int e = lane; e < E_; e += 64){
    float cv=c[e], v1=a1[e], v2=a2[e];
    d1+=v1*cv; d2+=v2*cv; cc+=cv*cv; n1+=v1*v1; n2+=v2*v2;
  }
  for (int off=32; off; off>>=1){
    d1+=__shfl_xor(d1,off); d2+=__shfl_xor(d2,off); cc+=__shfl_xor(cc,off);
    n1+=__shfl_xor(n1,off); n2+=__shfl_xor(n2,off);
  }
  if (lane == 0){
    float nc = sqrtf(cc);
    sim[(size_t)b*600 + k]       = d1 / fmaxf(sqrtf(n1)*nc, 1e-8f);
    sim[(size_t)b*600 + 300 + k] = d2 / fmaxf(sqrtf(n2)*nc, 1e-8f);
  }
}

// score = sim @ linW^T + linb; gold gather; argmax (first-max tie rule)
__global__ __launch_bounds__(256) void final_kernel(
    const float* __restrict__ sim, const float* __restrict__ linW,
    const float* __restrict__ linb, const int* __restrict__ idx,
    float* __restrict__ out){
  int b = blockIdx.x;
  __shared__ float ss[600];
  __shared__ float sc[300];
  __shared__ float bv[256];
  __shared__ int   bi[256];
  for (int j = threadIdx.x; j < 600; j += 256) ss[j] = sim[(size_t)b*600 + j];
  __syncthreads();
  float bestv = -1e30f; int besti = 0;
  for (int i = threadIdx.x; i < 300; i += 256){
    const float4* wr = (const float4*)(linW + (size_t)i*600);
    float acc = linb[i];
    for (int j4=0; j4<150; j4++){
      float4 w = wr[j4];
      int j = j4*4;
      acc += w.x*ss[j] + w.y*ss[j+1] + w.z*ss[j+2] + w.w*ss[j+3];
    }
    sc[i] = acc;
    out[64 + (size_t)b*300 + i] = acc;
    if (acc > bestv){ bestv = acc; besti = i; }
  }
  bv[threadIdx.x] = bestv; bi[threadIdx.x] = besti;
  __syncthreads();
  for (int s=128; s; s>>=1){
    if (threadIdx.x < s){
      float ov = bv[threadIdx.x+s]; int oi = bi[threadIdx.x+s];
      if (ov > bv[threadIdx.x] || (ov == bv[threadIdx.x] && oi < bi[threadIdx.x])){
        bv[threadIdx.x] = ov; bi[threadIdx.x] = oi;
      }
    }
    __syncthreads();
  }
  if (threadIdx.x == 0){
    out[b] = sc[idx[b]-1];
    out[64 + 64*300 + b] = (float)bi[0];
  }
}

extern "C" void kernel_launch(void* const* d_in, const int* in_sizes, int n_in,
                              void* d_out, int out_size, void* d_ws, size_t ws_size,
                              hipStream_t stream){
  const int*   docs  = (const int*)d_in[0];
  const int*   sens  = (const int*)d_in[1];
  const int*   cand  = (const int*)d_in[2];
  const int*   idx   = (const int*)d_in[3];
  const float* wemb  = (const float*)d_in[4];
  const float* eemb  = (const float*)d_in[5];
  const float* Wih_w = (const float*)d_in[6];
  const float* Whh_w = (const float*)d_in[7];
  const float* bih_w = (const float*)d_in[8];
  const float* bhh_w = (const float*)d_in[9];
  const float* attW_w= (const float*)d_in[10];
  const float* attb_w= (const float*)d_in[11];
  const float* ctx_w = (const float*)d_in[12];
  const float* Wih_s = (const float*)d_in[13];
  const float* Whh_s = (const float*)d_in[14];
  const float* bih_s = (const float*)d_in[15];
  const float* bhh_s = (const float*)d_in[16];
  const float* attW_s= (const float*)d_in[17];
  const float* attb_s= (const float*)d_in[18];
  const float* ctx_s = (const float*)d_in[19];
  const float* linW  = (const float*)d_in[20];
  const float* linb  = (const float*)d_in[21];

  float* ws = (float*)d_ws;
  size_t off = 0;
  float* gi_w    = ws + off; off += (size_t)T_*NW_*900;   // 176.9 MB
  float* hs_w    = ws + off; off += (size_t)T_*NW_*G_;    // 59 MB
  float* score_w = ws + off; off += (size_t)T_*NW_;
  float* sv      = ws + off; off += (size_t)NW_*G_;
  float* gi_s    = ws + off; off += (size_t)S_*B_*900;
  float* hs_s    = ws + off; off += (size_t)S_*B_*G_;
  float* score_s = ws + off; off += (size_t)S_*B_;
  float* odoc    = ws + off; off += (size_t)B_*G_;
  float* sim     = ws + off; off += (size_t)B_*600;

  float* out = (float*)d_out;

  // word level
  word_gi_kernel<<<RW_/16, 256, 0, stream>>>(docs, wemb, Wih_w, bih_w, gi_w);
  gru_scan_kernel<8,512><<<dim3(NW_/8, 2), 512, 0, stream>>>(gi_w, Whh_w, bhh_w,
                                                             hs_w, T_, NW_);
  att_score_kernel<<<(RW_+47)/48, 256, 0, stream>>>(hs_w, attW_w, attb_w,
                                                    ctx_w, score_w, RW_);
  att_combine_kernel<<<NW_, 256, 0, stream>>>(score_w, hs_w, sv, T_, NW_);

  // sentence level
  sent_gi_kernel<<<RS_/16, 256, 0, stream>>>(sv, Wih_s, bih_s, gi_s);
  gru_scan_kernel<4,512><<<dim3(B_/4, 2), 512, 0, stream>>>(gi_s, Whh_s, bhh_s,
                                                            hs_s, S_, B_);
  att_score_kernel<<<(RS_+47)/48, 256, 0, stream>>>(hs_s, attW_s, attb_s,
                                                    ctx_s, score_s, RS_);
  att_combine_kernel<<<B_, 256, 0, stream>>>(score_s, hs_s, odoc, S_, B_);

  // similarity + linear + gold + argmax
  cossim_kernel<<<(B_*NC_*64)/256, 256, 0, stream>>>(cand, sens, eemb, sv, odoc, sim);
  final_kernel<<<B_, 256, 0, stream>>>(sim, linW, linb, idx, out);
}

// Round 4
// 1539.020 us; speedup vs baseline: 1.9485x; 1.2841x over previous
//
#include <hip/hip_runtime.h>
#include <hip/hip_bf16.h>
#include <math.h>

#define B_  64
#define S_  16
#define T_  48
#define E_  300
#define H_  150
#define G_  300   // 2H
#define NC_ 300
#define NW_ (B_*S_)     // 1024 word-level batch
#define RW_ (T_*NW_)    // 49152 word rows
#define RS_ (S_*B_)     // 1024 sentence rows

__device__ __forceinline__ float sigm(float x){ return 1.0f/(1.0f+__expf(-x)); }

// ---------------------------------------------------------------------------
// transpose: in[R][C] -> out[C][R]
// ---------------------------------------------------------------------------
__global__ __launch_bounds__(256) void transpose_kernel(
    const float* __restrict__ in, float* __restrict__ out, int R, int C){
  int idx = blockIdx.x*256 + threadIdx.x;
  if (idx >= R*C) return;
  int j = idx % R, e = idx / R;
  out[idx] = in[(size_t)j*C + e];   // out[e][j]
}

// ---------------------------------------------------------------------------
// gi[t][n][j] = emb[docs[n,t]] @ Wih^T + bih, via K-major Wt[300][900].
// 16 rows/block; A tile in LDS (broadcast); W chunks [4][900] double-buffered,
// staged coalesced; thread q<225 owns 4 cols. One barrier per chunk.
// ---------------------------------------------------------------------------
__global__ __launch_bounds__(256,3) void word_gi_v2(
    const int* __restrict__ docs, const float* __restrict__ emb,
    const float* __restrict__ Wt, const float* __restrict__ bih,
    float* __restrict__ gi){
  __shared__ float A[16][304];
  __shared__ float Wc[2][4*900];
  int r0 = blockIdx.x * 16;
  int t  = r0 >> 10;
  int nb = r0 & 1023;
  for (int idx = threadIdx.x; idx < 16*75; idx += 256){
    int row = idx/75, e4 = idx - row*75;
    int tok = docs[(nb+row)*T_ + t];
    *(float4*)&A[row][e4*4] = *(const float4*)&emb[(size_t)tok*E_ + e4*4];
  }
  const float4* Wt4 = (const float4*)Wt;
  {
    float4* Wb0 = (float4*)Wc[0];
    for (int i4 = threadIdx.x; i4 < 900; i4 += 256) Wb0[i4] = Wt4[i4];
  }
  __syncthreads();
  int q = threadIdx.x;
  float acc[16][4] = {};
  float4 pf0, pf1, pf2, pf3;
  for (int c = 0; c < 75; ++c){
    int cur = c & 1;
    if (c < 74){
      const float4* src = Wt4 + (size_t)(c+1)*900;
      pf0 = src[q]; pf1 = src[q+256]; pf2 = src[q+512];
      if (q < 132) pf3 = src[q+768];
    }
    if (q < 225){
      const float4* wrow = (const float4*)Wc[cur];
      float4 w0 = wrow[q], w1 = wrow[225+q], w2 = wrow[450+q], w3 = wrow[675+q];
#pragma unroll
      for (int i = 0; i < 16; ++i){
        float4 av = *(const float4*)&A[i][c*4];
        acc[i][0] += av.x*w0.x + av.y*w1.x + av.z*w2.x + av.w*w3.x;
        acc[i][1] += av.x*w0.y + av.y*w1.y + av.z*w2.y + av.w*w3.y;
        acc[i][2] += av.x*w0.z + av.y*w1.z + av.z*w2.z + av.w*w3.z;
        acc[i][3] += av.x*w0.w + av.y*w1.w + av.z*w2.w + av.w*w3.w;
      }
    }
    if (c < 74){
      float4* Wbn = (float4*)Wc[cur^1];
      Wbn[q] = pf0; Wbn[q+256] = pf1; Wbn[q+512] = pf2;
      if (q < 132) Wbn[q+768] = pf3;
    }
    __syncthreads();
  }
  if (q < 225){
    int j0 = q*4;
    float4 bb = *(const float4*)&bih[j0];
#pragma unroll
    for (int i = 0; i < 16; ++i){
      float4 o4;
      o4.x = acc[i][0]+bb.x; o4.y = acc[i][1]+bb.y;
      o4.z = acc[i][2]+bb.z; o4.w = acc[i][3]+bb.w;
      *(float4*)&gi[((size_t)(t*NW_) + nb + i)*900 + j0] = o4;
    }
  }
}

// sentence-level gi (tiny: 64 blocks) — unchanged uncoalesced version
__global__ __launch_bounds__(256) void sent_gi_kernel(
    const float* __restrict__ sv, const float* __restrict__ Wih,
    const float* __restrict__ bih, float* __restrict__ gi){
  __shared__ float A[16][G_];
  int r0 = blockIdx.x * 16;
  int s  = r0 >> 6;
  int bb_ = r0 & 63;
  for (int idx = threadIdx.x; idx < 16*75; idx += 256){
    int row = idx / 75, e4 = idx - row*75;
    *(float4*)&A[row][e4*4] =
        *(const float4*)&sv[(((size_t)(bb_+row))*S_ + s)*G_ + e4*4];
  }
  __syncthreads();
  int q = threadIdx.x;
  if (q >= 225) return;
  int j0 = q*4;
  const float4* w0 = (const float4*)(Wih + (size_t)(j0  )*G_);
  const float4* w1 = (const float4*)(Wih + (size_t)(j0+1)*G_);
  const float4* w2 = (const float4*)(Wih + (size_t)(j0+2)*G_);
  const float4* w3 = (const float4*)(Wih + (size_t)(j0+3)*G_);
  float acc[16][4];
#pragma unroll
  for (int i=0;i<16;i++){ acc[i][0]=0.f; acc[i][1]=0.f; acc[i][2]=0.f; acc[i][3]=0.f; }
  for (int e4=0; e4<75; e4++){
    float4 b0=w0[e4], b1=w1[e4], b2=w2[e4], b3=w3[e4];
#pragma unroll
    for (int i=0;i<16;i++){
      float4 av = *(const float4*)&A[i][e4*4];
      acc[i][0] += av.x*b0.x + av.y*b0.y + av.z*b0.z + av.w*b0.w;
      acc[i][1] += av.x*b1.x + av.y*b1.y + av.z*b1.z + av.w*b1.w;
      acc[i][2] += av.x*b2.x + av.y*b2.y + av.z*b2.z + av.w*b2.w;
      acc[i][3] += av.x*b3.x + av.y*b3.y + av.z*b3.z + av.w*b3.w;
    }
  }
  float4 bb = *(const float4*)&bih[j0];
#pragma unroll
  for (int i=0;i<16;i++){
    float4 o4;
    o4.x = acc[i][0]+bb.x; o4.y = acc[i][1]+bb.y;
    o4.z = acc[i][2]+bb.z; o4.w = acc[i][3]+bb.w;
    *(float4*)&gi[((size_t)(s*B_) + bb_ + i)*900 + j0] = o4;
  }
}

// ---------------------------------------------------------------------------
// Persistent GRU scan (unchanged from round 3)
// ---------------------------------------------------------------------------
template<int R, int TPB>
__global__ __launch_bounds__(TPB) void gru_scan_kernel(
    const float* __restrict__ gi, const float* __restrict__ Whh,
    const float* __restrict__ bhh, float* __restrict__ hs,
    int T, int N){
  constexpr int EW = (R*H_ + TPB - 1)/TPB;
  int d  = blockIdx.y;
  int n0 = blockIdx.x * R;
  __shared__ float hl[R][152];
  __shared__ float gh[R][452];
  for (int idx = threadIdx.x; idx < R*H_; idx += TPB)
    hl[idx/H_][idx%H_] = 0.f;
  __syncthreads();
  int q = threadIdx.x;
  const float* wrow = nullptr; float bb = 0.f;
  if (q < 450){
    wrow = Whh + (size_t)d*450*H_ + (size_t)q*H_;
    bb   = bhh[d*450 + q];
  }
  for (int step=0; step<T; ++step){
    int t = d ? (T-1-step) : step;
    const float* gib = gi + ((size_t)t*N + n0)*900 + d*450;
    float pre[EW][3];
#pragma unroll
    for (int u=0; u<EW; ++u){
      int idx = q + u*TPB;
      if (idx < R*H_){
        int i = idx/H_, h = idx - i*H_;
        const float* g0 = gib + (size_t)i*900 + h;
        pre[u][0] = g0[0];
        pre[u][1] = g0[150];
        pre[u][2] = g0[300];
      }
    }
    if (q < 450){
      float a[R];
#pragma unroll
      for (int i=0;i<R;i++) a[i]=0.f;
      const float4* w4 = (const float4*)wrow;
#pragma unroll 4
      for (int e4=0; e4<37; ++e4){
        float4 wv = w4[e4];
#pragma unroll
        for (int i=0;i<R;i++){
          float4 hv = *(const float4*)&hl[i][e4*4];
          a[i] += wv.x*hv.x + wv.y*hv.y + wv.z*hv.z + wv.w*hv.w;
        }
      }
      float2 wt = *(const float2*)&wrow[148];
#pragma unroll
      for (int i=0;i<R;i++){
        float2 ht = *(const float2*)&hl[i][148];
        a[i] += wt.x*ht.x + wt.y*ht.y;
      }
#pragma unroll
      for (int i=0;i<R;i++) gh[i][q] = a[i] + bb;
    }
    __syncthreads();
#pragma unroll
    for (int u=0; u<EW; ++u){
      int idx = q + u*TPB;
      if (idx < R*H_){
        int i = idx/H_, h = idx - i*H_;
        float r  = sigm(pre[u][0] + gh[i][h]);
        float z  = sigm(pre[u][1] + gh[i][150+h]);
        float nn = tanhf(pre[u][2] + r*gh[i][300+h]);
        float h2 = (1.f - z)*nn + z*hl[i][h];
        hl[i][h] = h2;
        hs[((size_t)t*N + n0 + i)*G_ + d*H_ + h] = h2;
      }
    }
    __syncthreads();
  }
}

// ---------------------------------------------------------------------------
// score[r] = ctx . tanh(hs[r] @ W^T + b) via K-major Wt[300][300].
// 48 rows/block; W chunks [4][300] double-buffered coalesced.
// thread tid<225: rg=tid/75 (16-row group), q=tid%75 (4 cols).
// ---------------------------------------------------------------------------
__global__ __launch_bounds__(256,2) void att_score_v2(
    const float* __restrict__ hs, const float* __restrict__ Wt,
    const float* __restrict__ bias, const float* __restrict__ ctx,
    float* __restrict__ score, int Rtot){
  __shared__ float A[48][304];
  __shared__ float Wc[2][4*300];
  int r0 = blockIdx.x * 48;
  for (int idx = threadIdx.x; idx < 48*75; idx += 256){
    int row = idx/75, e4 = idx - row*75;
    float4 v; v.x=0.f; v.y=0.f; v.z=0.f; v.w=0.f;
    if (r0 + row < Rtot) v = *(const float4*)&hs[(size_t)(r0+row)*G_ + e4*4];
    *(float4*)&A[row][e4*4] = v;
  }
  const float4* Wt4 = (const float4*)Wt;
  {
    float4* Wb0 = (float4*)Wc[0];
    for (int i4 = threadIdx.x; i4 < 300; i4 += 256) Wb0[i4] = Wt4[i4];
  }
  __syncthreads();
  int tid = threadIdx.x;
  int rg = tid/75, q = tid - rg*75;
  float acc[16][4] = {};
  float4 pf0, pf1;
  for (int c = 0; c < 75; ++c){
    int cur = c & 1;
    if (c < 74){
      const float4* src = Wt4 + (size_t)(c+1)*300;
      pf0 = src[tid];
      if (tid < 44) pf1 = src[tid+256];
    }
    if (tid < 225){
      const float4* wrow = (const float4*)Wc[cur];
      float4 w0 = wrow[q], w1 = wrow[75+q], w2 = wrow[150+q], w3 = wrow[225+q];
      const float* Ab = &A[rg*16][0];
#pragma unroll
      for (int i = 0; i < 16; ++i){
        float4 av = *(const float4*)&Ab[(size_t)i*304 + c*4];
        acc[i][0] += av.x*w0.x + av.y*w1.x + av.z*w2.x + av.w*w3.x;
        acc[i][1] += av.x*w0.y + av.y*w1.y + av.z*w2.y + av.w*w3.y;
        acc[i][2] += av.x*w0.z + av.y*w1.z + av.z*w2.z + av.w*w3.z;
        acc[i][3] += av.x*w0.w + av.y*w1.w + av.z*w2.w + av.w*w3.w;
      }
    }
    if (c < 74){
      float4* Wbn = (float4*)Wc[cur^1];
      Wbn[tid] = pf0;
      if (tid < 44) Wbn[tid+256] = pf1;
    }
    __syncthreads();
  }
  float part[16];
  if (tid < 225){
    int h0 = q*4;
    float4 bb = *(const float4*)&bias[h0];
    float4 cx = *(const float4*)&ctx[h0];
#pragma unroll
    for (int i = 0; i < 16; ++i){
      part[i] = cx.x*tanhf(acc[i][0]+bb.x) + cx.y*tanhf(acc[i][1]+bb.y)
              + cx.z*tanhf(acc[i][2]+bb.z) + cx.w*tanhf(acc[i][3]+bb.w);
    }
  }
  __syncthreads();
  float* Af = &A[0][0];
  if (tid < 225){
#pragma unroll
    for (int i = 0; i < 16; ++i) Af[q*48 + rg*16 + i] = part[i];
  }
  __syncthreads();
  if (tid < 48 && r0 + tid < Rtot){
    float s = 0.f;
    for (int q2 = 0; q2 < 75; ++q2) s += Af[q2*48 + tid];
    score[r0 + tid] = s;
  }
}

// softmax over t (per n) + weighted sum
__global__ __launch_bounds__(256) void att_combine_kernel(
    const float* __restrict__ score, const float* __restrict__ hs,
    float* __restrict__ out, int T, int N){
  int n = blockIdx.x;
  __shared__ float wa[64];
  if (threadIdx.x < T) wa[threadIdx.x] = score[threadIdx.x*N + n];
  __syncthreads();
  float m = -1e30f;
  for (int t=0;t<T;t++) m = fmaxf(m, wa[t]);
  float den = 0.f;
  for (int t=0;t<T;t++) den += __expf(wa[t]-m);
  float inv = 1.f/den;
  __syncthreads();
  if (threadIdx.x < T) wa[threadIdx.x] = __expf(wa[threadIdx.x]-m)*inv;
  __syncthreads();
  for (int g = threadIdx.x; g < G_; g += 256){
    float acc = 0.f;
    for (int t=0;t<T;t++) acc += wa[t] * hs[((size_t)t*N+n)*G_ + g];
    out[(size_t)n*G_ + g] = acc;
  }
}

// one wave per (b,k): both cosine sims
__global__ __launch_bounds__(256) void cossim_kernel(
    const int* __restrict__ cand, const int* __restrict__ sens,
    const float* __restrict__ ent, const float* __restrict__ sv,
    const float* __restrict__ odoc, float* __restrict__ sim){
  int w = (blockIdx.x*256 + threadIdx.x) >> 6;
  int lane = threadIdx.x & 63;
  if (w >= B_*NC_) return;
  int b = w / NC_, k = w - b*NC_;
  const float* c  = ent + (size_t)cand[b*NC_ + k]*E_;
  const float* a1 = sv  + ((size_t)b*S_ + sens[b])*G_;
  const float* a2 = odoc + (size_t)b*G_;
  float d1=0.f,d2=0.f,cc=0.f,n1=0.f,n2=0.f;
  for (int e = lane; e < E_; e += 64){
    float cv=c[e], v1=a1[e], v2=a2[e];
    d1+=v1*cv; d2+=v2*cv; cc+=cv*cv; n1+=v1*v1; n2+=v2*v2;
  }
  for (int off=32; off; off>>=1){
    d1+=__shfl_xor(d1,off); d2+=__shfl_xor(d2,off); cc+=__shfl_xor(cc,off);
    n1+=__shfl_xor(n1,off); n2+=__shfl_xor(n2,off);
  }
  if (lane == 0){
    float nc = sqrtf(cc);
    sim[(size_t)b*600 + k]       = d1 / fmaxf(sqrtf(n1)*nc, 1e-8f);
    sim[(size_t)b*600 + 300 + k] = d2 / fmaxf(sqrtf(n2)*nc, 1e-8f);
  }
}

// score = sim @ linW^T + linb; gold gather; argmax (first-max tie rule)
__global__ __launch_bounds__(256) void final_kernel(
    const float* __restrict__ sim, const float* __restrict__ linW,
    const float* __restrict__ linb, const int* __restrict__ idx,
    float* __restrict__ out){
  int b = blockIdx.x;
  __shared__ float ss[600];
  __shared__ float sc[300];
  __shared__ float bv[256];
  __shared__ int   bi[256];
  for (int j = threadIdx.x; j < 600; j += 256) ss[j] = sim[(size_t)b*600 + j];
  __syncthreads();
  float bestv = -1e30f; int besti = 0;
  for (int i = threadIdx.x; i < 300; i += 256){
    const float4* wr = (const float4*)(linW + (size_t)i*600);
    float acc = linb[i];
    for (int j4=0; j4<150; j4++){
      float4 w = wr[j4];
      int j = j4*4;
      acc += w.x*ss[j] + w.y*ss[j+1] + w.z*ss[j+2] + w.w*ss[j+3];
    }
    sc[i] = acc;
    out[64 + (size_t)b*300 + i] = acc;
    if (acc > bestv){ bestv = acc; besti = i; }
  }
  bv[threadIdx.x] = bestv; bi[threadIdx.x] = besti;
  __syncthreads();
  for (int s=128; s; s>>=1){
    if (threadIdx.x < s){
      float ov = bv[threadIdx.x+s]; int oi = bi[threadIdx.x+s];
      if (ov > bv[threadIdx.x] || (ov == bv[threadIdx.x] && oi < bi[threadIdx.x])){
        bv[threadIdx.x] = ov; bi[threadIdx.x] = oi;
      }
    }
    __syncthreads();
  }
  if (threadIdx.x == 0){
    out[b] = sc[idx[b]-1];
    out[64 + 64*300 + b] = (float)bi[0];
  }
}

extern "C" void kernel_launch(void* const* d_in, const int* in_sizes, int n_in,
                              void* d_out, int out_size, void* d_ws, size_t ws_size,
                              hipStream_t stream){
  const int*   docs  = (const int*)d_in[0];
  const int*   sens  = (const int*)d_in[1];
  const int*   cand  = (const int*)d_in[2];
  const int*   idx   = (const int*)d_in[3];
  const float* wemb  = (const float*)d_in[4];
  const float* eemb  = (const float*)d_in[5];
  const float* Wih_w = (const float*)d_in[6];
  const float* Whh_w = (const float*)d_in[7];
  const float* bih_w = (const float*)d_in[8];
  const float* bhh_w = (const float*)d_in[9];
  const float* attW_w= (const float*)d_in[10];
  const float* attb_w= (const float*)d_in[11];
  const float* ctx_w = (const float*)d_in[12];
  const float* Wih_s = (const float*)d_in[13];
  const float* Whh_s = (const float*)d_in[14];
  const float* bih_s = (const float*)d_in[15];
  const float* bhh_s = (const float*)d_in[16];
  const float* attW_s= (const float*)d_in[17];
  const float* attb_s= (const float*)d_in[18];
  const float* ctx_s = (const float*)d_in[19];
  const float* linW  = (const float*)d_in[20];
  const float* linb  = (const float*)d_in[21];

  float* ws = (float*)d_ws;
  size_t off = 0;
  float* gi_w    = ws + off; off += (size_t)T_*NW_*900;   // 176.9 MB
  float* hs_w    = ws + off; off += (size_t)T_*NW_*G_;    // 59 MB
  float* score_w = ws + off; off += (size_t)T_*NW_;
  float* sv      = ws + off; off += (size_t)NW_*G_;
  float* gi_s    = ws + off; off += (size_t)S_*B_*900;
  float* hs_s    = ws + off; off += (size_t)S_*B_*G_;
  float* score_s = ws + off; off += (size_t)S_*B_;
  float* odoc    = ws + off; off += (size_t)B_*G_;
  float* sim     = ws + off; off += (size_t)B_*600;
  float* Wt_w    = ws + off; off += (size_t)900*300;      // [300][900]
  float* WtA_w   = ws + off; off += (size_t)300*300;      // [300][300]
  float* WtA_s   = ws + off; off += (size_t)300*300;

  float* out = (float*)d_out;

  // one-time weight transposes (K-major)
  transpose_kernel<<<(900*300+255)/256, 256, 0, stream>>>(Wih_w, Wt_w, 900, 300);
  transpose_kernel<<<(300*300+255)/256, 256, 0, stream>>>(attW_w, WtA_w, 300, 300);
  transpose_kernel<<<(300*300+255)/256, 256, 0, stream>>>(attW_s, WtA_s, 300, 300);

  // word level
  word_gi_v2<<<RW_/16, 256, 0, stream>>>(docs, wemb, Wt_w, bih_w, gi_w);
  gru_scan_kernel<8,512><<<dim3(NW_/8, 2), 512, 0, stream>>>(gi_w, Whh_w, bhh_w,
                                                             hs_w, T_, NW_);
  att_score_v2<<<(RW_+47)/48, 256, 0, stream>>>(hs_w, WtA_w, attb_w,
                                                ctx_w, score_w, RW_);
  att_combine_kernel<<<NW_, 256, 0, stream>>>(score_w, hs_w, sv, T_, NW_);

  // sentence level
  sent_gi_kernel<<<RS_/16, 256, 0, stream>>>(sv, Wih_s, bih_s, gi_s);
  gru_scan_kernel<4,512><<<dim3(B_/4, 2), 512, 0, stream>>>(gi_s, Whh_s, bhh_s,
                                                            hs_s, S_, B_);
  att_score_v2<<<(RS_+47)/48, 256, 0, stream>>>(hs_s, WtA_s, attb_s,
                                                ctx_s, score_s, RS_);
  att_combine_kernel<<<B_, 256, 0, stream>>>(score_s, hs_s, odoc, S_, B_);

  // similarity + linear + gold + argmax
  cossim_kernel<<<(B_*NC_*64)/256, 256, 0, stream>>>(cand, sens, eemb, sv, odoc, sim);
  final_kernel<<<B_, 256, 0, stream>>>(sim, linW, linb, idx, out);
}